// Round 1
// baseline (222.467 us; speedup 1.0000x reference)
//
#include <hip/hip_runtime.h>
#include <hip/hip_cooperative_groups.h>

namespace cg = cooperative_groups;

#define DIM 64
#define NVOX (DIM * DIM * DIM)
#define EPF 53248          // boundary edges per field
#define HV 1000            // 10*10*10 halo

// ---------------------------------------------------------------------------
// Lock-free union-find (ECL-CC style), works on global OR LDS int arrays.
// Invariant: every stored parent is a strictly-smaller-index ancestor ->
// stale reads still see valid ancestors; atomicCAS is the coherent ground
// truth; failed CAS returns a strictly smaller value -> guaranteed
// termination.
// ---------------------------------------------------------------------------
__device__ __forceinline__ int find_root_link(int* L, int v) {
    for (;;) {
        int p = L[v];
        if (p == v) return v;
        int gp = L[p];
        if (gp == p) return p;
        L[v] = gp;   // path-halving: writes an ancestor, races benign
        v = gp;
    }
}

__device__ __forceinline__ void unite(int* L, int a, int b) {
    int ra = find_root_link(L, a);
    int rb = find_root_link(L, b);
    while (ra != rb) {
        if (ra > rb) { int t = ra; ra = rb; rb = t; }
        int old = atomicCAS(&L[rb], rb, ra);
        if (old == rb) break;            // hooked rb -> ra
        rb = find_root_link(L, old);     // old coherent, strictly < rb
        ra = find_root_link(L, ra);
    }
}

// read-only chase (no writes; valid ancestor even under concurrent unites)
__device__ __forceinline__ int chase(const int* __restrict__ L, int p) {
    int q = L[p];
    while (q != p) { p = q; q = L[p]; }
    return p;
}

// ---------------------------------------------------------------------------
// 27-bit 3x3x3 mask connectivity via branch-free separable dilation.
// Bit index = z*9 + y*3 + x.
// ---------------------------------------------------------------------------
#define MX_L 0x6DB6DB6u   // result x in {1,2}
#define MX_R 0x36DB6DBu   // result x in {0,1}
#define MY_L 0x7E3F1F8u   // result y in {1,2}
#define MY_R 0x0FC7E3Fu   // result y in {0,1}
#define M27  0x7FFFFFFu

__device__ __forceinline__ unsigned dil26(unsigned m) {
    m |= ((m << 1) & MX_L) | ((m >> 1) & MX_R);
    m |= ((m << 3) & MY_L) | ((m >> 3) & MY_R);
    m |= ((m << 9) & M27)  | (m >> 9);
    return m;
}
__device__ __forceinline__ unsigned dil18(unsigned m) {
    unsigned ax = m | ((m << 1) & MX_L) | ((m >> 1) & MX_R);          // Dx
    unsigned ay = m | ((m << 3) & MY_L) | ((m >> 3) & MY_R);          // Dy
    unsigned dxy = ax | ((ax << 3) & MY_L) | ((ax >> 3) & MY_R);      // DyDx
    unsigned dxz = ax | ((ax << 9) & M27)  | (ax >> 9);               // DzDx
    unsigned dyz = ay | ((ay << 9) & M27)  | (ay >> 9);               // DzDy
    return dxy | dxz | dyz;   // all offsets with >=1 zero component
}

__device__ __forceinline__ bool single18(unsigned m) {
    if (!m) return false;
    unsigned c = m & (~m + 1u);
    for (;;) {
        unsigned n = dil18(c) & m;
        if (n == m) return true;
        if (n == c) return false;
        c = n;
    }
}
__device__ __forceinline__ bool single26(unsigned m) {
    if (!m) return false;
    unsigned c = m & (~m + 1u);
    for (;;) {
        unsigned n = dil26(c) & m;
        if (n == m) return true;
        if (n == c) return false;
        c = n;
    }
}

// ---------------------------------------------------------------------------
// Fused cooperative kernel. Grid = 512 blocks x 256 threads, 2 blocks/CU.
//
// Phase 1 (blocks 0..255): per-tile CCL in LDS. Tile 16x16x8 = 2048 voxels,
//   4 x-contiguous voxels per thread per group (2 groups) -> float4 loads,
//   int4 label stores. Writes global label = global index of tile-local root
//   (monotone map keeps parent <= child globally).
// grid.sync()
// Phase 2 (threads 0..EPF-1): cross-tile edge list, raw-pair dedupe before
//   the dependent chase, root-pair dedupe before unite (both fields/thread).
// grid.sync()
// Phase 3 (all 512 blocks): 8x8x8 region per block, 10x10x10 chased-root
//   halo in LDS, 27-bit-mask simple-point test, weighted BCE + mean.
//
// LDS: union of phase-1 tile labels (2048 ints) and phase-3 halos (2x1000).
// ---------------------------------------------------------------------------
__global__ __launch_bounds__(256, 2)
void fused_all(const float* __restrict__ pred, const float* __restrict__ lab,
               int* __restrict__ LP, int* __restrict__ LL,
               float* __restrict__ out) {
    __shared__ union {
        int tile[2048];                       // phase 1
        struct { int P[HV]; int L[HV]; } h;   // phase 3
    } sm;
    __shared__ float s_part[4];

    cg::grid_group grid = cg::this_grid();
    const int t = threadIdx.x;
    const int b = blockIdx.x;

    if (b == 0 && t == 0) *out = 0.0f;       // ordered before phase-3 atomics
                                             // by the two grid.sync()s below

    // ---------------- Phase 1: per-tile CCL ----------------
    if (b < 256) {
        int tile = b & 127, field = b >> 7;   // 128 tiles: 4 x 4 x 8
        int tx = tile & 3, ty = (tile >> 2) & 3, tz = tile >> 4;
        int X0 = tx << 4, Y0 = ty << 4, Z0 = tz << 3;
        const float* src = field ? lab : pred;
        int* Lg = field ? LL : LP;

        bool fg[8];
        int vbase[2];
#pragma unroll
        for (int j = 0; j < 2; ++j) {
            int l0 = (j << 10) | (t << 2);    // 4 x-contiguous voxels
            int lx = l0 & 15, ly = (l0 >> 4) & 15, lz = l0 >> 8;
            int v0 = ((Z0 + lz) << 12) | ((Y0 + ly) << 6) | (X0 + lx);
            vbase[j] = v0;
            const float4 f = *reinterpret_cast<const float4*>(src + v0);
            int4 s;
            fg[j * 4 + 0] = f.x > 0.0f; s.x = fg[j * 4 + 0] ? l0 + 0 : -1;
            fg[j * 4 + 1] = f.y > 0.0f; s.y = fg[j * 4 + 1] ? l0 + 1 : -1;
            fg[j * 4 + 2] = f.z > 0.0f; s.z = fg[j * 4 + 2] ? l0 + 2 : -1;
            fg[j * 4 + 3] = f.w > 0.0f; s.w = fg[j * 4 + 3] ? l0 + 3 : -1;
            *reinterpret_cast<int4*>(&sm.tile[l0]) = s;
        }
        __syncthreads();

#pragma unroll
        for (int j = 0; j < 2; ++j) {
#pragma unroll
            for (int k = 0; k < 4; ++k) {
                if (!fg[j * 4 + k]) continue;
                int l = ((j << 10) | (t << 2)) + k;
                int lx = l & 15, ly = (l >> 4) & 15, lz = l >> 8;
                if (lx < 15 && sm.tile[l + 1]   >= 0) unite(sm.tile, l, l + 1);
                if (ly < 15 && sm.tile[l + 16]  >= 0) unite(sm.tile, l, l + 16);
                if (lz < 7  && sm.tile[l + 256] >= 0) unite(sm.tile, l, l + 256);
            }
        }
        __syncthreads();

#pragma unroll
        for (int j = 0; j < 2; ++j) {
            int l0 = (j << 10) | (t << 2);
            int rr[4];
#pragma unroll
            for (int k = 0; k < 4; ++k) {
                int g = -1;
                if (fg[j * 4 + k]) {
                    int p = sm.tile[l0 + k];
                    while (sm.tile[p] != p) p = sm.tile[p];  // read-only chase
                    g = ((Z0 + (p >> 8)) << 12) | ((Y0 + ((p >> 4) & 15)) << 6)
                      | (X0 + (p & 15));
                }
                rr[k] = g;
            }
            *reinterpret_cast<int4*>(Lg + vbase[j]) =
                make_int4(rr[0], rr[1], rr[2], rr[3]);
        }
    }

    grid.sync();

    // ---------------- Phase 2: cross-tile boundary edges ----------------
    {
        int e = (b << 8) | t;                 // 0..131071; EPF active
        if (e < EPF) {
            int v, n;
            if (e < 12288) {                  // x-faces: planes 15,31,47
                int plane = 15 + ((e >> 12) << 4);
                int ij = e & 4095;            // y = ij&63 (lane-consecutive)
                v = ((ij >> 6) << 12) | ((ij & 63) << 6) | plane;
                n = v + 1;
            } else if (e < 24576) {           // y-faces: planes 15,31,47
                int e2 = e - 12288;
                int plane = 15 + ((e2 >> 12) << 4);
                int ij = e2 & 4095;
                v = ((ij >> 6) << 12) | (plane << 6) | (ij & 63);
                n = v + 64;
            } else {                          // z-faces: planes 7..55
                int e3 = e - 24576;
                int plane = 7 + ((e3 >> 12) << 3);
                int ij = e3 & 4095;
                v = (plane << 12) | ((ij >> 6) << 6) | (ij & 63);
                n = v + 4096;
            }

            int lane = t & 63;
            int pa = LP[v], pb = LP[n];
            int la = LL[v], lb = LL[n];
            bool doP = (pa >= 0) & (pb >= 0);
            bool doL = (la >= 0) & (lb >= 0);

            // raw-pair dedupe (kills the dependent chase for run-duplicates)
            int xpa = __shfl_up(pa, 1, 64), xpb = __shfl_up(pb, 1, 64);
            int xla = __shfl_up(la, 1, 64), xlb = __shfl_up(lb, 1, 64);
            if (lane && xpa == pa && xpb == pb) doP = false;
            if (lane && xla == la && xlb == lb) doL = false;

            int rp0 = -1, rp1 = -1, rl0 = -1, rl1 = -1;
            if (doP) {
                int u0 = chase(LP, pa), u1 = chase(LP, pb);
                rp0 = min(u0, u1); rp1 = max(u0, u1);
            }
            if (doL) {
                int u0 = chase(LL, la), u1 = chase(LL, lb);
                rl0 = min(u0, u1); rl1 = max(u0, u1);
            }

            // root-pair dedupe (different raw pairs may share final roots)
            int qp0 = __shfl_up(rp0, 1, 64), qp1 = __shfl_up(rp1, 1, 64);
            int ql0 = __shfl_up(rl0, 1, 64), ql1 = __shfl_up(rl1, 1, 64);
            bool dupP = lane && (qp0 == rp0) && (qp1 == rp1);
            bool dupL = lane && (ql0 == rl0) && (ql1 == rl1);

            if (rp0 >= 0 && rp0 != rp1 && !dupP) unite(LP, rp0, rp1);
            if (rl0 >= 0 && rl0 != rl1 && !dupL) unite(LL, rl0, rl1);
        }
    }

    grid.sync();

    // ---------------- Phase 3: non-simple maps + weighted BCE ----------------
    {
        int rx = b & 7, ry = (b >> 3) & 7, rz = b >> 6;   // 8x8x8 regions
        int x0 = rx << 3, y0 = ry << 3, z0 = rz << 3;

        // batched halo load: all independent loads first, then the chases
        int pv[4], lv[4];
#pragma unroll
        for (int j = 0; j < 4; ++j) {
            int i = t + (j << 8);
            if (i < HV) {
                int hx = i % 10, rr = i / 10, hy = rr % 10, hz = rr / 10;
                int gx = x0 + hx - 1; gx = gx < 0 ? 0 : (gx > 63 ? 63 : gx);
                int gy = y0 + hy - 1; gy = gy < 0 ? 0 : (gy > 63 ? 63 : gy);
                int gz = z0 + hz - 1; gz = gz < 0 ? 0 : (gz > 63 ? 63 : gz);
                int gv = (gz << 12) | (gy << 6) | gx;
                pv[j] = LP[gv];
                lv[j] = LL[gv];
            }
        }
#pragma unroll
        for (int j = 0; j < 4; ++j) {
            int i = t + (j << 8);
            if (i < HV) {
                int p = pv[j];
                if (p >= 0) p = chase(LP, p);
                sm.h.P[i] = p;
                p = lv[j];
                if (p >= 0) p = chase(LL, p);
                sm.h.L[i] = p;
            }
        }
        __syncthreads();

        float acc = 0.0f;
#pragma unroll
        for (int j = 0; j < 2; ++j) {
            int l = t + (j << 8);                // region 8x8x8: 512 voxels
            int lx = l & 7, ly = (l >> 3) & 7, lz = l >> 6;
            int x = x0 | lx, y = y0 | ly, z = z0 | lz;
            int v = (z << 12) | (y << 6) | x;
            int base = lz * 100 + ly * 10 + lx;  // (-1,-1,-1) corner

            bool nsP = false, nsL = false;
            {
                int c = sm.h.P[base + 111];      // center
                if (c >= 0) {
                    unsigned m1 = 0, m2 = 0; int k = 0;
#pragma unroll
                    for (int kz = 0; kz < 3; ++kz)
#pragma unroll
                        for (int ky = 0; ky < 3; ++ky)
#pragma unroll
                            for (int kx = 0; kx < 3; ++kx, ++k) {
                                int w = sm.h.P[base + kz * 100 + ky * 10 + kx];
                                m1 |= (unsigned)(w != c) << k;
                                m2 |= (unsigned)(w == c) << k;
                            }
                    m2 &= ~(1u << 13);           // drop center
                    nsP = !(single18(m1) && single26(m2));
                }
            }
            {
                int c = sm.h.L[base + 111];
                if (c >= 0) {
                    unsigned m1 = 0, m2 = 0; int k = 0;
#pragma unroll
                    for (int kz = 0; kz < 3; ++kz)
#pragma unroll
                        for (int ky = 0; ky < 3; ++ky)
#pragma unroll
                            for (int kx = 0; kx < 3; ++kx, ++k) {
                                int w = sm.h.L[base + kz * 100 + ky * 10 + kx];
                                m1 |= (unsigned)(w != c) << k;
                                m2 |= (unsigned)(w == c) << k;
                            }
                    m2 &= ~(1u << 13);
                    nsL = !(single18(m1) && single26(m2));
                }
            }

            float p = pred[v], lvf = lab[v];
            float cost = fmaxf(p, 0.0f) - p * lvf + log1pf(__expf(-fabsf(p)));
            acc += ((nsP || nsL) ? 5.0f : 1.0f) * cost;
        }

#pragma unroll
        for (int off = 32; off > 0; off >>= 1)
            acc += __shfl_down(acc, off, 64);
        if ((t & 63) == 0) s_part[t >> 6] = acc;
        __syncthreads();
        if (t == 0) {
            float s = s_part[0] + s_part[1] + s_part[2] + s_part[3];
            atomicAdd(out, s * (1.0f / (float)NVOX));
        }
    }
}

extern "C" void kernel_launch(void* const* d_in, const int* in_sizes, int n_in,
                              void* d_out, int out_size, void* d_ws, size_t ws_size,
                              hipStream_t stream) {
    const float* pred = (const float*)d_in[0];   // 'prediction'
    const float* lab  = (const float*)d_in[1];   // 'label'
    float* out = (float*)d_out;

    int* LP = (int*)d_ws;          // NVOX ints
    int* LL = LP + NVOX;           // NVOX ints  (2 MiB total)

    void* args[] = { (void*)&pred, (void*)&lab, (void*)&LP, (void*)&LL,
                     (void*)&out };
    hipLaunchCooperativeKernel((const void*)fused_all, dim3(512), dim3(256),
                               args, 0, stream);
}

// Round 2
// 109.190 us; speedup vs baseline: 2.0374x; 2.0374x over previous
//
#include <hip/hip_runtime.h>

#define DIM 64
#define NVOX (DIM * DIM * DIM)
#define EPF 53248          // boundary edges per field

// ---------------------------------------------------------------------------
// Lock-free union-find (ECL-CC style), works on global OR LDS int arrays.
// Invariant: every stored parent is a strictly-smaller-index ancestor ->
// stale (non-coherent L1) reads still see valid ancestors; atomicCAS is the
// coherent ground truth; failed CAS returns a strictly smaller value ->
// guaranteed termination.
// ---------------------------------------------------------------------------
__device__ __forceinline__ int find_root_link(int* L, int v) {
    for (;;) {
        int p = L[v];
        if (p == v) return v;
        int gp = L[p];
        if (gp == p) return p;
        L[v] = gp;   // path-halving: writes an ancestor, races benign
        v = gp;
    }
}

__device__ __forceinline__ void unite(int* L, int a, int b) {
    int ra = find_root_link(L, a);
    int rb = find_root_link(L, b);
    while (ra != rb) {
        if (ra > rb) { int t = ra; ra = rb; rb = t; }
        int old = atomicCAS(&L[rb], rb, ra);
        if (old == rb) break;            // hooked rb -> ra
        rb = find_root_link(L, old);     // old coherent, strictly < rb
        ra = find_root_link(L, ra);
    }
}

// read-only chase (no writes; valid ancestor even under concurrent unites)
__device__ __forceinline__ int chase(const int* __restrict__ L, int p) {
    int q = L[p];
    while (q != p) { p = q; q = L[p]; }
    return p;
}

// ---------------------------------------------------------------------------
// Phase 1: per-tile CCL in LDS. Tile 16x16x8 = 2048 voxels, 512 threads
// (4 x-contiguous voxels/thread -> float4 load, int4 store), grid
// (128 tiles, 2 fields). 8 waves/block = 2 waves/SIMD (R2: was 1).
// Writes global label = global index of tile-local root (monotone map keeps
// parent <= child globally). Block (0,0) also zeroes d_out (ordered before
// finalize's atomics by the dispatch boundaries).
// ---------------------------------------------------------------------------
__global__ __launch_bounds__(512)
void local_ccl(const float* __restrict__ pred,
               const float* __restrict__ lab,
               int* __restrict__ LP, int* __restrict__ LL,
               float* __restrict__ out) {
    __shared__ int s_lab[2048];
    int t = threadIdx.x;
    if (blockIdx.x == 0 && blockIdx.y == 0 && t == 0) *out = 0.0f;
    int b = blockIdx.x;                         // 128 tiles: 4 x 4 x 8
    int tx = b & 3, ty = (b >> 2) & 3, tz = b >> 4;
    int X0 = tx << 4, Y0 = ty << 4, Z0 = tz << 3;

    const float* src = blockIdx.y ? lab : pred;
    int* Lg = blockIdx.y ? LL : LP;

    int l0 = t << 2;                            // 4 x-contiguous voxels
    int lx0 = l0 & 15, ly0 = (l0 >> 4) & 15, lz0 = l0 >> 8;
    int v0 = ((Z0 + lz0) << 12) | ((Y0 + ly0) << 6) | (X0 + lx0);

    bool fg[4];
    {
        const float4 f = *reinterpret_cast<const float4*>(src + v0);
        int4 s;
        fg[0] = f.x > 0.0f; s.x = fg[0] ? l0 + 0 : -1;
        fg[1] = f.y > 0.0f; s.y = fg[1] ? l0 + 1 : -1;
        fg[2] = f.z > 0.0f; s.z = fg[2] ? l0 + 2 : -1;
        fg[3] = f.w > 0.0f; s.w = fg[3] ? l0 + 3 : -1;
        *reinterpret_cast<int4*>(&s_lab[l0]) = s;
    }
    __syncthreads();

#pragma unroll
    for (int k = 0; k < 4; ++k) {
        if (!fg[k]) continue;
        int l = l0 + k;
        int lx = l & 15, ly = (l >> 4) & 15, lz = l >> 8;
        if (lx < 15 && s_lab[l + 1]   >= 0) unite(s_lab, l, l + 1);
        if (ly < 15 && s_lab[l + 16]  >= 0) unite(s_lab, l, l + 16);
        if (lz < 7  && s_lab[l + 256] >= 0) unite(s_lab, l, l + 256);
    }
    __syncthreads();

    {
        int rr[4];
#pragma unroll
        for (int k = 0; k < 4; ++k) {
            int g = -1;
            if (fg[k]) {
                int p = s_lab[l0 + k];
                while (s_lab[p] != p) p = s_lab[p];  // read-only chase
                g = ((Z0 + (p >> 8)) << 12) | ((Y0 + ((p >> 4) & 15)) << 6)
                  | (X0 + (p & 15));
            }
            rr[k] = g;
        }
        *reinterpret_cast<int4*>(Lg + v0) = make_int4(rr[0], rr[1], rr[2], rr[3]);
    }
}

// ---------------------------------------------------------------------------
// Phase 2: compact cross-tile edge list, one thread per geometric edge,
// both fields per thread. Dedupe on the RAW tile-component pair BEFORE
// chasing (consecutive edges along a face mostly connect the same pair of
// local components), then dedupe on final roots before unite. Raw labels
// may be mid-halving values; any stored value is a valid ancestor, so a
// missed dedupe is only a tiny redundancy, never an error.
// ---------------------------------------------------------------------------
__global__ __launch_bounds__(256)
void boundary_link(int* __restrict__ LP, int* __restrict__ LL) {
    int r = blockIdx.x * blockDim.x + threadIdx.x;   // 0..EPF-1
    int v, n;
    if (r < 12288) {                             // x-faces: planes 15,31,47
        int plane = 15 + ((r >> 12) << 4);
        int ij = r & 4095;                       // y = ij&63 (lane-consecutive)
        v = ((ij >> 6) << 12) | ((ij & 63) << 6) | plane;
        n = v + 1;
    } else if (r < 24576) {                      // y-faces: planes 15,31,47
        int r2 = r - 12288;
        int plane = 15 + ((r2 >> 12) << 4);
        int ij = r2 & 4095;                      // x = ij&63, z = ij>>6
        v = ((ij >> 6) << 12) | (plane << 6) | (ij & 63);
        n = v + 64;
    } else {                                     // z-faces: planes 7..55
        int r3 = r - 24576;
        int plane = 7 + ((r3 >> 12) << 3);
        int ij = r3 & 4095;                      // x = ij&63, y = ij>>6
        v = (plane << 12) | ((ij >> 6) << 6) | (ij & 63);
        n = v + 4096;
    }

    int lane = threadIdx.x & 63;

    int pa = LP[v], pb = LP[n];
    int la = LL[v], lb = LL[n];
    bool doP = (pa >= 0) & (pb >= 0);
    bool doL = (la >= 0) & (lb >= 0);

    // raw-pair dedupe (kills the chase for run-duplicates)
    int xpa = __shfl_up(pa, 1, 64), xpb = __shfl_up(pb, 1, 64);
    int xla = __shfl_up(la, 1, 64), xlb = __shfl_up(lb, 1, 64);
    if (lane && xpa == pa && xpb == pb) doP = false;
    if (lane && xla == la && xlb == lb) doL = false;

    int rp0 = -1, rp1 = -1, rl0 = -1, rl1 = -1;
    if (doP) {
        int u0 = chase(LP, pa), u1 = chase(LP, pb);
        rp0 = min(u0, u1); rp1 = max(u0, u1);
    }
    if (doL) {
        int u0 = chase(LL, la), u1 = chase(LL, lb);
        rl0 = min(u0, u1); rl1 = max(u0, u1);
    }

    // root-pair dedupe (different raw pairs may share final roots)
    int qp0 = __shfl_up(rp0, 1, 64), qp1 = __shfl_up(rp1, 1, 64);
    int ql0 = __shfl_up(rl0, 1, 64), ql1 = __shfl_up(rl1, 1, 64);
    bool dupP = lane && (qp0 == rp0) && (qp1 == rp1);
    bool dupL = lane && (ql0 == rl0) && (ql1 == rl1);

    if (rp0 >= 0 && rp0 != rp1 && !dupP) unite(LP, rp0, rp1);
    if (rl0 >= 0 && rl0 != rl1 && !dupL) unite(LL, rl0, rl1);
}

// ---------------------------------------------------------------------------
// Phase 2.5 (R2, new): flatten both label arrays to final roots.
// Fully parallel, full occupancy; does each voxel's chase exactly ONCE
// (finalize's overlapping halos previously chased ~2x NVOX with only
// 2 blocks/CU). After this, every stored label IS the final root.
// Writing the root preserves the parent<=child invariant trivially.
// ---------------------------------------------------------------------------
__global__ __launch_bounds__(256)
void flatten(int* __restrict__ LP, int* __restrict__ LL) {
    int idx = blockIdx.x * blockDim.x + threadIdx.x;   // 0..2*NVOX-1
    int* L = (idx < NVOX) ? LP : LL;
    int i = idx & (NVOX - 1);
    int p = L[i];
    if (p >= 0) {
        int r = chase(L, p);
        if (r != p) L[i] = r;
    }
}

// ---------------------------------------------------------------------------
// 27-bit 3x3x3 mask connectivity via branch-free separable dilation.
// Bit index = z*9 + y*3 + x.
// ---------------------------------------------------------------------------
#define MX_L 0x6DB6DB6u   // result x in {1,2}
#define MX_R 0x36DB6DBu   // result x in {0,1}
#define MY_L 0x7E3F1F8u   // result y in {1,2}
#define MY_R 0x0FC7E3Fu   // result y in {0,1}
#define M27  0x7FFFFFFu

__device__ __forceinline__ unsigned dil26(unsigned m) {
    m |= ((m << 1) & MX_L) | ((m >> 1) & MX_R);
    m |= ((m << 3) & MY_L) | ((m >> 3) & MY_R);
    m |= ((m << 9) & M27)  | (m >> 9);
    return m;
}
__device__ __forceinline__ unsigned dil18(unsigned m) {
    unsigned ax = m | ((m << 1) & MX_L) | ((m >> 1) & MX_R);          // Dx
    unsigned ay = m | ((m << 3) & MY_L) | ((m >> 3) & MY_R);          // Dy
    unsigned dxy = ax | ((ax << 3) & MY_L) | ((ax >> 3) & MY_R);      // DyDx
    unsigned dxz = ax | ((ax << 9) & M27)  | (ax >> 9);               // DzDx
    unsigned dyz = ay | ((ay << 9) & M27)  | (ay >> 9);               // DzDy
    return dxy | dxz | dyz;   // all offsets with >=1 zero component
}

__device__ __forceinline__ bool single18(unsigned m) {
    if (!m) return false;
    unsigned c = m & (~m + 1u);
    for (;;) {
        unsigned n = dil18(c) & m;
        if (n == m) return true;
        if (n == c) return false;
        c = n;
    }
}
__device__ __forceinline__ bool single26(unsigned m) {
    if (!m) return false;
    unsigned c = m & (~m + 1u);
    for (;;) {
        unsigned n = dil26(c) & m;
        if (n == m) return true;
        if (n == c) return false;
        c = n;
    }
}

// ---------------------------------------------------------------------------
// Phase 3: non-simple maps + weighted BCE + mean.
// R2: region 8x8x4 per block (1024 blocks = 4 blocks/CU = 16 waves/CU,
// 1 voxel/thread/field), halo 10x10x6 = 600 ints per field. Labels are
// pre-flattened -> halo load is a PURE load (no dependent chase).
// Halo layout: i = hz*100 + hy*10 + hx; window corner of (lx,ly,lz) = base,
// center = base + 111.
// ---------------------------------------------------------------------------
#define HV2 600   // 10*10*6

__global__ __launch_bounds__(256, 4)
void finalize_kernel(const float* __restrict__ pred,
                     const float* __restrict__ lab,
                     const int* __restrict__ LP,
                     const int* __restrict__ LL,
                     float* __restrict__ out) {
    __shared__ int sP[HV2], sL[HV2];
    __shared__ float s_part[4];
    int t = threadIdx.x;
    int b = blockIdx.x;                          // 8 x 8 x 16 regions
    int rx = b & 7, ry = (b >> 3) & 7, rz = b >> 6;
    int x0 = rx << 3, y0 = ry << 3, z0 = rz << 2;

    // batched halo load (no chases: labels are final roots already)
    int pv[3], lv[3];
#pragma unroll
    for (int j = 0; j < 3; ++j) {
        int i = t + (j << 8);
        if (i < HV2) {
            int hx = i % 10, rr = i / 10, hy = rr % 10, hz = rr / 10;
            int gx = x0 + hx - 1; gx = gx < 0 ? 0 : (gx > 63 ? 63 : gx);
            int gy = y0 + hy - 1; gy = gy < 0 ? 0 : (gy > 63 ? 63 : gy);
            int gz = z0 + hz - 1; gz = gz < 0 ? 0 : (gz > 63 ? 63 : gz);
            int gv = (gz << 12) | (gy << 6) | gx;
            pv[j] = LP[gv];
            lv[j] = LL[gv];
        }
    }
#pragma unroll
    for (int j = 0; j < 3; ++j) {
        int i = t + (j << 8);
        if (i < HV2) {
            sP[i] = pv[j];
            sL[i] = lv[j];
        }
    }
    __syncthreads();

    float acc;
    {
        int l = t;                               // region 8x8x4: 256 voxels
        int lx = l & 7, ly = (l >> 3) & 7, lz = l >> 6;
        int x = x0 | lx, y = y0 | ly, z = z0 | lz;
        int v = (z << 12) | (y << 6) | x;
        int base = lz * 100 + ly * 10 + lx;      // (-1,-1,-1) corner

        bool nsP = false, nsL = false;
        {
            int c = sP[base + 111];              // center
            if (c >= 0) {
                unsigned m1 = 0, m2 = 0; int k = 0;
#pragma unroll
                for (int kz = 0; kz < 3; ++kz)
#pragma unroll
                    for (int ky = 0; ky < 3; ++ky)
#pragma unroll
                        for (int kx = 0; kx < 3; ++kx, ++k) {
                            int w = sP[base + kz * 100 + ky * 10 + kx];
                            m1 |= (unsigned)(w != c) << k;
                            m2 |= (unsigned)(w == c) << k;
                        }
                m2 &= ~(1u << 13);               // drop center
                nsP = !(single18(m1) && single26(m2));
            }
        }
        {
            int c = sL[base + 111];
            if (c >= 0) {
                unsigned m1 = 0, m2 = 0; int k = 0;
#pragma unroll
                for (int kz = 0; kz < 3; ++kz)
#pragma unroll
                    for (int ky = 0; ky < 3; ++ky)
#pragma unroll
                        for (int kx = 0; kx < 3; ++kx, ++k) {
                            int w = sL[base + kz * 100 + ky * 10 + kx];
                            m1 |= (unsigned)(w != c) << k;
                            m2 |= (unsigned)(w == c) << k;
                        }
                m2 &= ~(1u << 13);
                nsL = !(single18(m1) && single26(m2));
            }
        }

        float p = pred[v], lvf = lab[v];
        float cost = fmaxf(p, 0.0f) - p * lvf + log1pf(__expf(-fabsf(p)));
        acc = ((nsP || nsL) ? 5.0f : 1.0f) * cost;
    }

#pragma unroll
    for (int off = 32; off > 0; off >>= 1)
        acc += __shfl_down(acc, off, 64);
    if ((t & 63) == 0) s_part[t >> 6] = acc;
    __syncthreads();
    if (t == 0) {
        float s = s_part[0] + s_part[1] + s_part[2] + s_part[3];
        atomicAdd(out, s * (1.0f / (float)NVOX));
    }
}

extern "C" void kernel_launch(void* const* d_in, const int* in_sizes, int n_in,
                              void* d_out, int out_size, void* d_ws, size_t ws_size,
                              hipStream_t stream) {
    const float* pred = (const float*)d_in[0];   // 'prediction'
    const float* lab  = (const float*)d_in[1];   // 'label'
    float* out = (float*)d_out;

    int* LP = (int*)d_ws;          // NVOX ints
    int* LL = LP + NVOX;           // NVOX ints  (2 MiB total)

    hipLaunchKernelGGL(local_ccl, dim3(128, 2), dim3(512), 0, stream,
                       pred, lab, LP, LL, out);
    hipLaunchKernelGGL(boundary_link, dim3(EPF / 256), dim3(256), 0, stream,
                       LP, LL);
    hipLaunchKernelGGL(flatten, dim3(2 * NVOX / 256), dim3(256), 0, stream,
                       LP, LL);
    hipLaunchKernelGGL(finalize_kernel, dim3(1024), dim3(256), 0, stream,
                       pred, lab, LP, LL, out);
}

// Round 3
// 104.203 us; speedup vs baseline: 2.1349x; 1.0478x over previous
//
#include <hip/hip_runtime.h>

#define DIM 64
#define NVOX (DIM * DIM * DIM)
#define EPF 53248          // boundary edges per field

// ---------------------------------------------------------------------------
// Lock-free union-find (ECL-CC style), works on global OR LDS int arrays.
// Invariant: every stored parent is a strictly-smaller-index ancestor ->
// stale (non-coherent L1) reads still see valid ancestors; atomicCAS is the
// coherent ground truth; failed CAS returns a strictly smaller value ->
// guaranteed termination.
// ---------------------------------------------------------------------------
__device__ __forceinline__ int find_root_link(int* L, int v) {
    for (;;) {
        int p = L[v];
        if (p == v) return v;
        int gp = L[p];
        if (gp == p) return p;
        L[v] = gp;   // path-halving: writes an ancestor, races benign
        v = gp;
    }
}

__device__ __forceinline__ void unite(int* L, int a, int b) {
    int ra = find_root_link(L, a);
    int rb = find_root_link(L, b);
    while (ra != rb) {
        if (ra > rb) { int t = ra; ra = rb; rb = t; }
        int old = atomicCAS(&L[rb], rb, ra);
        if (old == rb) break;            // hooked rb -> ra
        rb = find_root_link(L, old);     // old coherent, strictly < rb
        ra = find_root_link(L, ra);
    }
}

// read-only chase (no writes; valid ancestor even under concurrent unites)
__device__ __forceinline__ int chase(const int* __restrict__ L, int p) {
    int q = L[p];
    while (q != p) { p = q; q = L[p]; }
    return p;
}

// ---------------------------------------------------------------------------
// Phase 1: per-tile CCL in LDS. Tile 16x16x8 = 2048 voxels, 512 threads,
// 4 x-contiguous voxels/thread (float4 load, int4 store).
// R3: ROW-RUN SEEDING -- each voxel's initial label is the head of its
// x-run (from a 16-bit row mask: 2x shfl_xor OR-reduce + clz). This
// pre-merges all x-adjacency (no x-unites at all), halves the component
// count entering the CAS phase, and shortens every chase. y/z unites skip
// consecutive repeats of the same (run,run) pair within the thread.
// Writes global label = global index of tile-local root (monotone map keeps
// parent <= child globally). Block (0,0) also zeroes d_out.
// ---------------------------------------------------------------------------
__global__ __launch_bounds__(512)
void local_ccl(const float* __restrict__ pred,
               const float* __restrict__ lab,
               int* __restrict__ LP, int* __restrict__ LL,
               float* __restrict__ out) {
    __shared__ int s_lab[2048];
    int t = threadIdx.x;
    if (blockIdx.x == 0 && blockIdx.y == 0 && t == 0) *out = 0.0f;
    int b = blockIdx.x;                         // 128 tiles: 4 x 4 x 8
    int tx = b & 3, ty = (b >> 2) & 3, tz = b >> 4;
    int X0 = tx << 4, Y0 = ty << 4, Z0 = tz << 3;

    const float* src = blockIdx.y ? lab : pred;
    int* Lg = blockIdx.y ? LL : LP;

    int l0 = t << 2;                            // 4 x-contiguous voxels
    int v0 = ((Z0 + (l0 >> 8)) << 12) | ((Y0 + ((l0 >> 4) & 15)) << 6)
           | (X0 + (l0 & 15));

    // load 4 voxels, build per-thread fg nibble
    unsigned nib;
    {
        const float4 f = *reinterpret_cast<const float4*>(src + v0);
        nib  = (unsigned)(f.x > 0.0f);
        nib |= (unsigned)(f.y > 0.0f) << 1;
        nib |= (unsigned)(f.z > 0.0f) << 2;
        nib |= (unsigned)(f.w > 0.0f) << 3;
    }

    // 16-bit row mask: OR nibbles across the aligned 4-thread group
    unsigned rm = nib << ((t & 3) << 2);
    rm |= __shfl_xor(rm, 1, 64);
    rm |= __shfl_xor(rm, 2, 64);

    int rowbase = l0 & ~15;                     // row start voxel (local)
    int xbase = l0 & 15;                        // this thread's first x in row

    // seed labels = run head (branch-free)
    {
        int4 s;
        int lbl[4];
#pragma unroll
        for (int k = 0; k < 4; ++k) {
            int xpos = xbase + k;
            unsigned u = ~rm & ((1u << xpos) - 1u);   // zeros strictly below
            int start = u ? (32 - __clz(u)) : 0;      // (highest zero)+1
            lbl[k] = ((nib >> k) & 1) ? rowbase + start : -1;
        }
        s.x = lbl[0]; s.y = lbl[1]; s.z = lbl[2]; s.w = lbl[3];
        *reinterpret_cast<int4*>(&s_lab[l0]) = s;
    }
    __syncthreads();

    // y/z unites only (x handled by run seeding), with repeated-pair skip
    {
        int py_a = -2, py_b = -2;               // previous y-pair (impossible)
        int pz_a = -2, pz_b = -2;
#pragma unroll
        for (int k = 0; k < 4; ++k) {
            if (!((nib >> k) & 1)) continue;
            int l = l0 + k;
            int a = s_lab[l];                   // this run's head (stable)
            int ly = (l >> 4) & 15, lz = l >> 8;
            if (ly < 15) {
                int nb = s_lab[l + 16];
                if (nb >= 0 && !(a == py_a && nb == py_b)) {
                    unite(s_lab, a, nb);
                    py_a = a; py_b = nb;
                }
            }
            if (lz < 7) {
                int nb = s_lab[l + 256];
                if (nb >= 0 && !(a == pz_a && nb == pz_b)) {
                    unite(s_lab, a, nb);
                    pz_a = a; pz_b = nb;
                }
            }
        }
    }
    __syncthreads();

    // chase to tile root, write global labels
    {
        int rr[4];
#pragma unroll
        for (int k = 0; k < 4; ++k) {
            int g = -1;
            if ((nib >> k) & 1) {
                int p = s_lab[l0 + k];
                while (s_lab[p] != p) p = s_lab[p];  // read-only chase
                g = ((Z0 + (p >> 8)) << 12) | ((Y0 + ((p >> 4) & 15)) << 6)
                  | (X0 + (p & 15));
            }
            rr[k] = g;
        }
        *reinterpret_cast<int4*>(Lg + v0) = make_int4(rr[0], rr[1], rr[2], rr[3]);
    }
}

// ---------------------------------------------------------------------------
// Phase 2: compact cross-tile edge list, one thread per geometric edge.
// R3: one FIELD per block (blockIdx.y) instead of both fields per thread --
// the two dependent chase chains were serialized in program order; splitting
// halves the per-thread critical path and doubles TLP (208 -> 416 blocks).
// Dedupe on the RAW tile-root pair BEFORE chasing, then on final roots
// before unite. Raw labels are stable tile roots (phase 1 writes chased
// roots); any stored value is a valid ancestor, so a missed dedupe is only
// a tiny redundancy, never an error.
// ---------------------------------------------------------------------------
__global__ __launch_bounds__(256)
void boundary_link(int* __restrict__ LP, int* __restrict__ LL) {
    int r = blockIdx.x * blockDim.x + threadIdx.x;   // 0..EPF-1
    int* L = blockIdx.y ? LL : LP;

    int v, n;
    if (r < 12288) {                             // x-faces: planes 15,31,47
        int plane = 15 + ((r >> 12) << 4);
        int ij = r & 4095;                       // y = ij&63 (lane-consecutive)
        v = ((ij >> 6) << 12) | ((ij & 63) << 6) | plane;
        n = v + 1;
    } else if (r < 24576) {                      // y-faces: planes 15,31,47
        int r2 = r - 12288;
        int plane = 15 + ((r2 >> 12) << 4);
        int ij = r2 & 4095;                      // x = ij&63, z = ij>>6
        v = ((ij >> 6) << 12) | (plane << 6) | (ij & 63);
        n = v + 64;
    } else {                                     // z-faces: planes 7..55
        int r3 = r - 24576;
        int plane = 7 + ((r3 >> 12) << 3);
        int ij = r3 & 4095;                      // x = ij&63, y = ij>>6
        v = (plane << 12) | ((ij >> 6) << 6) | (ij & 63);
        n = v + 4096;
    }

    int lane = threadIdx.x & 63;

    int pa = L[v], pb = L[n];
    bool go = (pa >= 0) & (pb >= 0);

    // raw-pair dedupe (kills the chase for run-duplicates)
    int xpa = __shfl_up(pa, 1, 64), xpb = __shfl_up(pb, 1, 64);
    if (lane && xpa == pa && xpb == pb) go = false;

    int r0 = -1, r1 = -1;
    if (go) {
        int u0 = chase(L, pa), u1 = chase(L, pb);
        r0 = min(u0, u1); r1 = max(u0, u1);
    }

    // root-pair dedupe (different raw pairs may share final roots)
    int q0 = __shfl_up(r0, 1, 64), q1 = __shfl_up(r1, 1, 64);
    bool dup = lane && (q0 == r0) && (q1 == r1);

    if (r0 >= 0 && r0 != r1 && !dup) unite(L, r0, r1);
}

// ---------------------------------------------------------------------------
// Phase 2.5: flatten both label arrays to final roots. Fully parallel,
// full occupancy; each voxel's chase happens exactly once. After this,
// every stored label IS the final root (monotone invariant trivially kept).
// ---------------------------------------------------------------------------
__global__ __launch_bounds__(256)
void flatten(int* __restrict__ LP, int* __restrict__ LL) {
    int idx = blockIdx.x * blockDim.x + threadIdx.x;   // 0..2*NVOX-1
    int* L = (idx < NVOX) ? LP : LL;
    int i = idx & (NVOX - 1);
    int p = L[i];
    if (p >= 0) {
        int r = chase(L, p);
        if (r != p) L[i] = r;
    }
}

// ---------------------------------------------------------------------------
// 27-bit 3x3x3 mask connectivity via branch-free separable dilation.
// Bit index = z*9 + y*3 + x.
// ---------------------------------------------------------------------------
#define MX_L 0x6DB6DB6u   // result x in {1,2}
#define MX_R 0x36DB6DBu   // result x in {0,1}
#define MY_L 0x7E3F1F8u   // result y in {1,2}
#define MY_R 0x0FC7E3Fu   // result y in {0,1}
#define M27  0x7FFFFFFu

__device__ __forceinline__ unsigned dil26(unsigned m) {
    m |= ((m << 1) & MX_L) | ((m >> 1) & MX_R);
    m |= ((m << 3) & MY_L) | ((m >> 3) & MY_R);
    m |= ((m << 9) & M27)  | (m >> 9);
    return m;
}
__device__ __forceinline__ unsigned dil18(unsigned m) {
    unsigned ax = m | ((m << 1) & MX_L) | ((m >> 1) & MX_R);          // Dx
    unsigned ay = m | ((m << 3) & MY_L) | ((m >> 3) & MY_R);          // Dy
    unsigned dxy = ax | ((ax << 3) & MY_L) | ((ax >> 3) & MY_R);      // DyDx
    unsigned dxz = ax | ((ax << 9) & M27)  | (ax >> 9);               // DzDx
    unsigned dyz = ay | ((ay << 9) & M27)  | (ay >> 9);               // DzDy
    return dxy | dxz | dyz;   // all offsets with >=1 zero component
}

__device__ __forceinline__ bool single18(unsigned m) {
    if (!m) return false;
    unsigned c = m & (~m + 1u);
    for (;;) {
        unsigned n = dil18(c) & m;
        if (n == m) return true;
        if (n == c) return false;
        c = n;
    }
}
__device__ __forceinline__ bool single26(unsigned m) {
    if (!m) return false;
    unsigned c = m & (~m + 1u);
    for (;;) {
        unsigned n = dil26(c) & m;
        if (n == m) return true;
        if (n == c) return false;
        c = n;
    }
}

// ---------------------------------------------------------------------------
// Phase 3: non-simple maps + weighted BCE + mean.
// Region 8x8x4 per block (1024 blocks = 4 blocks/CU, 1 voxel/thread/field),
// halo 10x10x6 = 600 ints per field. Labels are pre-flattened -> halo load
// is a PURE load (no dependent chase). Halo layout: i = hz*100 + hy*10 + hx;
// window corner of (lx,ly,lz) = base, center = base + 111.
// ---------------------------------------------------------------------------
#define HV2 600   // 10*10*6

__global__ __launch_bounds__(256, 4)
void finalize_kernel(const float* __restrict__ pred,
                     const float* __restrict__ lab,
                     const int* __restrict__ LP,
                     const int* __restrict__ LL,
                     float* __restrict__ out) {
    __shared__ int sP[HV2], sL[HV2];
    __shared__ float s_part[4];
    int t = threadIdx.x;
    int b = blockIdx.x;                          // 8 x 8 x 16 regions
    int rx = b & 7, ry = (b >> 3) & 7, rz = b >> 6;
    int x0 = rx << 3, y0 = ry << 3, z0 = rz << 2;

    // batched halo load (no chases: labels are final roots already)
    int pv[3], lv[3];
#pragma unroll
    for (int j = 0; j < 3; ++j) {
        int i = t + (j << 8);
        if (i < HV2) {
            int hx = i % 10, rr = i / 10, hy = rr % 10, hz = rr / 10;
            int gx = x0 + hx - 1; gx = gx < 0 ? 0 : (gx > 63 ? 63 : gx);
            int gy = y0 + hy - 1; gy = gy < 0 ? 0 : (gy > 63 ? 63 : gy);
            int gz = z0 + hz - 1; gz = gz < 0 ? 0 : (gz > 63 ? 63 : gz);
            int gv = (gz << 12) | (gy << 6) | gx;
            pv[j] = LP[gv];
            lv[j] = LL[gv];
        }
    }
#pragma unroll
    for (int j = 0; j < 3; ++j) {
        int i = t + (j << 8);
        if (i < HV2) {
            sP[i] = pv[j];
            sL[i] = lv[j];
        }
    }
    __syncthreads();

    float acc;
    {
        int l = t;                               // region 8x8x4: 256 voxels
        int lx = l & 7, ly = (l >> 3) & 7, lz = l >> 6;
        int x = x0 | lx, y = y0 | ly, z = z0 | lz;
        int v = (z << 12) | (y << 6) | x;
        int base = lz * 100 + ly * 10 + lx;      // (-1,-1,-1) corner

        bool nsP = false, nsL = false;
        {
            int c = sP[base + 111];              // center
            if (c >= 0) {
                unsigned m1 = 0, m2 = 0; int k = 0;
#pragma unroll
                for (int kz = 0; kz < 3; ++kz)
#pragma unroll
                    for (int ky = 0; ky < 3; ++ky)
#pragma unroll
                        for (int kx = 0; kx < 3; ++kx, ++k) {
                            int w = sP[base + kz * 100 + ky * 10 + kx];
                            m1 |= (unsigned)(w != c) << k;
                            m2 |= (unsigned)(w == c) << k;
                        }
                m2 &= ~(1u << 13);               // drop center
                nsP = !(single18(m1) && single26(m2));
            }
        }
        {
            int c = sL[base + 111];
            if (c >= 0) {
                unsigned m1 = 0, m2 = 0; int k = 0;
#pragma unroll
                for (int kz = 0; kz < 3; ++kz)
#pragma unroll
                    for (int ky = 0; ky < 3; ++ky)
#pragma unroll
                        for (int kx = 0; kx < 3; ++kx, ++k) {
                            int w = sL[base + kz * 100 + ky * 10 + kx];
                            m1 |= (unsigned)(w != c) << k;
                            m2 |= (unsigned)(w == c) << k;
                        }
                m2 &= ~(1u << 13);
                nsL = !(single18(m1) && single26(m2));
            }
        }

        float p = pred[v], lvf = lab[v];
        float cost = fmaxf(p, 0.0f) - p * lvf + log1pf(__expf(-fabsf(p)));
        acc = ((nsP || nsL) ? 5.0f : 1.0f) * cost;
    }

#pragma unroll
    for (int off = 32; off > 0; off >>= 1)
        acc += __shfl_down(acc, off, 64);
    if ((t & 63) == 0) s_part[t >> 6] = acc;
    __syncthreads();
    if (t == 0) {
        float s = s_part[0] + s_part[1] + s_part[2] + s_part[3];
        atomicAdd(out, s * (1.0f / (float)NVOX));
    }
}

extern "C" void kernel_launch(void* const* d_in, const int* in_sizes, int n_in,
                              void* d_out, int out_size, void* d_ws, size_t ws_size,
                              hipStream_t stream) {
    const float* pred = (const float*)d_in[0];   // 'prediction'
    const float* lab  = (const float*)d_in[1];   // 'label'
    float* out = (float*)d_out;

    int* LP = (int*)d_ws;          // NVOX ints
    int* LL = LP + NVOX;           // NVOX ints  (2 MiB total)

    hipLaunchKernelGGL(local_ccl, dim3(128, 2), dim3(512), 0, stream,
                       pred, lab, LP, LL, out);
    hipLaunchKernelGGL(boundary_link, dim3(EPF / 256, 2), dim3(256), 0, stream,
                       LP, LL);
    hipLaunchKernelGGL(flatten, dim3(2 * NVOX / 256), dim3(256), 0, stream,
                       LP, LL);
    hipLaunchKernelGGL(finalize_kernel, dim3(1024), dim3(256), 0, stream,
                       pred, lab, LP, LL, out);
}

// Round 4
// 103.331 us; speedup vs baseline: 2.1529x; 1.0084x over previous
//
#include <hip/hip_runtime.h>

#define DIM 64
#define NVOX (DIM * DIM * DIM)
#define EPF 53248          // boundary edges per field

// ---------------------------------------------------------------------------
// Lock-free union-find, atomicMin hooking (Playne & Stepanyan 2018 style).
// Invariant: every stored parent is a <=-index member of the same (merging)
// component; atomicMin only ever lowers values, so stale reads still see a
// valid decreasing chain and every chase terminates. A "failed" hook
// (old != rb) delegates the residual merge (ra, old) to the next loop
// iteration; max(ra,rb) strictly decreases -> guaranteed termination.
// Works identically on LDS and global arrays (atomics are coherent).
// ---------------------------------------------------------------------------
__device__ __forceinline__ void unite(int* L, int a, int b) {
    int ra = a, rb = b;
    while (ra != rb) {
        if (ra > rb) { int t = ra; ra = rb; rb = t; }
        int old = atomicMin(&L[rb], ra);
        if (old == rb || old == ra) break;   // hooked a root / already linked
        rb = old;                            // continue merging (ra, old)
    }
}

// read-only chase (no writes; decreasing chain is valid under concurrency)
__device__ __forceinline__ int chase(const int* __restrict__ L, int p) {
    int q = L[p];
    while (q != p) { p = q; q = L[p]; }
    return p;
}

// ---------------------------------------------------------------------------
// Phase 1: per-tile CCL in LDS. Tile 16x16x8 = 2048 voxels, 512 threads,
// 4 x-contiguous voxels/thread (float4 load, int4 store).
// ROW-RUN SEEDING: each voxel's initial label is the head of its x-run
// (16-bit row mask via 2x shfl_xor OR-reduce + clz); pre-merges all
// x-adjacency, so only y/z unites remain (with consecutive-pair skip).
// Writes global label = global index of tile-local root (tile-local order
// equals global order within a tile -> parent <= child globally).
// Block (0,0) also zeroes d_out (ordered before finalize's atomics by the
// dispatch boundaries).
// ---------------------------------------------------------------------------
__global__ __launch_bounds__(512)
void local_ccl(const float* __restrict__ pred,
               const float* __restrict__ lab,
               int* __restrict__ LP, int* __restrict__ LL,
               float* __restrict__ out) {
    __shared__ int s_lab[2048];
    int t = threadIdx.x;
    if (blockIdx.x == 0 && blockIdx.y == 0 && t == 0) *out = 0.0f;
    int b = blockIdx.x;                         // 128 tiles: 4 x 4 x 8
    int tx = b & 3, ty = (b >> 2) & 3, tz = b >> 4;
    int X0 = tx << 4, Y0 = ty << 4, Z0 = tz << 3;

    const float* src = blockIdx.y ? lab : pred;
    int* Lg = blockIdx.y ? LL : LP;

    int l0 = t << 2;                            // 4 x-contiguous voxels
    int v0 = ((Z0 + (l0 >> 8)) << 12) | ((Y0 + ((l0 >> 4) & 15)) << 6)
           | (X0 + (l0 & 15));

    // load 4 voxels, build per-thread fg nibble
    unsigned nib;
    {
        const float4 f = *reinterpret_cast<const float4*>(src + v0);
        nib  = (unsigned)(f.x > 0.0f);
        nib |= (unsigned)(f.y > 0.0f) << 1;
        nib |= (unsigned)(f.z > 0.0f) << 2;
        nib |= (unsigned)(f.w > 0.0f) << 3;
    }

    // 16-bit row mask: OR nibbles across the aligned 4-thread group
    unsigned rm = nib << ((t & 3) << 2);
    rm |= __shfl_xor(rm, 1, 64);
    rm |= __shfl_xor(rm, 2, 64);

    int rowbase = l0 & ~15;                     // row start voxel (local)
    int xbase = l0 & 15;                        // this thread's first x in row

    // seed labels = run head (branch-free)
    {
        int4 s;
        int lbl[4];
#pragma unroll
        for (int k = 0; k < 4; ++k) {
            int xpos = xbase + k;
            unsigned u = ~rm & ((1u << xpos) - 1u);   // zeros strictly below
            int start = u ? (32 - __clz(u)) : 0;      // (highest zero)+1
            lbl[k] = ((nib >> k) & 1) ? rowbase + start : -1;
        }
        s.x = lbl[0]; s.y = lbl[1]; s.z = lbl[2]; s.w = lbl[3];
        *reinterpret_cast<int4*>(&s_lab[l0]) = s;
    }
    __syncthreads();

    // y/z unites only (x handled by run seeding), with repeated-pair skip
    {
        int py_a = -2, py_b = -2;               // previous y-pair (impossible)
        int pz_a = -2, pz_b = -2;
#pragma unroll
        for (int k = 0; k < 4; ++k) {
            if (!((nib >> k) & 1)) continue;
            int l = l0 + k;
            int a = s_lab[l0 + k] >= 0 ? (l0 + k, s_lab[l]) : -1;
            a = s_lab[l];                       // this run's head (stable)
            int ly = (l >> 4) & 15, lz = l >> 8;
            if (ly < 15) {
                int nb = s_lab[l + 16];
                if (nb >= 0 && !(a == py_a && nb == py_b)) {
                    unite(s_lab, a, nb);
                    py_a = a; py_b = nb;
                }
            }
            if (lz < 7) {
                int nb = s_lab[l + 256];
                if (nb >= 0 && !(a == pz_a && nb == pz_b)) {
                    unite(s_lab, a, nb);
                    pz_a = a; pz_b = nb;
                }
            }
        }
    }
    __syncthreads();

    // chase to tile root, write global labels
    {
        int rr[4];
#pragma unroll
        for (int k = 0; k < 4; ++k) {
            int g = -1;
            if ((nib >> k) & 1) {
                int p = s_lab[l0 + k];
                while (s_lab[p] != p) p = s_lab[p];  // read-only chase
                g = ((Z0 + (p >> 8)) << 12) | ((Y0 + ((p >> 4) & 15)) << 6)
                  | (X0 + (p & 15));
            }
            rr[k] = g;
        }
        *reinterpret_cast<int4*>(Lg + v0) = make_int4(rr[0], rr[1], rr[2], rr[3]);
    }
}

// ---------------------------------------------------------------------------
// Phase 2: compact cross-tile edge list, one thread per geometric edge,
// one FIELD per blockIdx.y (halves the per-thread dependent-chase chain,
// doubles TLP). Dedupe on the RAW tile-root pair BEFORE chasing, then on
// final roots before unite. Raw labels are stable tile roots; any stored
// value is a valid ancestor, so a missed dedupe is only a tiny redundancy,
// never an error.
// ---------------------------------------------------------------------------
__global__ __launch_bounds__(256)
void boundary_link(int* __restrict__ LP, int* __restrict__ LL) {
    int r = blockIdx.x * blockDim.x + threadIdx.x;   // 0..EPF-1
    int* L = blockIdx.y ? LL : LP;

    int v, n;
    if (r < 12288) {                             // x-faces: planes 15,31,47
        int plane = 15 + ((r >> 12) << 4);
        int ij = r & 4095;                       // y = ij&63 (lane-consecutive)
        v = ((ij >> 6) << 12) | ((ij & 63) << 6) | plane;
        n = v + 1;
    } else if (r < 24576) {                      // y-faces: planes 15,31,47
        int r2 = r - 12288;
        int plane = 15 + ((r2 >> 12) << 4);
        int ij = r2 & 4095;                      // x = ij&63, z = ij>>6
        v = ((ij >> 6) << 12) | (plane << 6) | (ij & 63);
        n = v + 64;
    } else {                                     // z-faces: planes 7..55
        int r3 = r - 24576;
        int plane = 7 + ((r3 >> 12) << 3);
        int ij = r3 & 4095;                      // x = ij&63, y = ij>>6
        v = (plane << 12) | ((ij >> 6) << 6) | (ij & 63);
        n = v + 4096;
    }

    int lane = threadIdx.x & 63;

    int pa = L[v], pb = L[n];
    bool go = (pa >= 0) & (pb >= 0);

    // raw-pair dedupe (kills the chase for run-duplicates)
    int xpa = __shfl_up(pa, 1, 64), xpb = __shfl_up(pb, 1, 64);
    if (lane && xpa == pa && xpb == pb) go = false;

    int r0 = -1, r1 = -1;
    if (go) {
        int u0 = chase(L, pa), u1 = chase(L, pb);
        r0 = min(u0, u1); r1 = max(u0, u1);
    }

    // root-pair dedupe (different raw pairs may share final roots)
    int q0 = __shfl_up(r0, 1, 64), q1 = __shfl_up(r1, 1, 64);
    bool dup = lane && (q0 == r0) && (q1 == r1);

    if (r0 >= 0 && r0 != r1 && !dup) unite(L, r0, r1);
}

// ---------------------------------------------------------------------------
// 27-bit 3x3x3 mask connectivity via branch-free separable dilation.
// Bit index = z*9 + y*3 + x.
// ---------------------------------------------------------------------------
#define MX_L 0x6DB6DB6u   // result x in {1,2}
#define MX_R 0x36DB6DBu   // result x in {0,1}
#define MY_L 0x7E3F1F8u   // result y in {1,2}
#define MY_R 0x0FC7E3Fu   // result y in {0,1}
#define M27  0x7FFFFFFu

__device__ __forceinline__ unsigned dil26(unsigned m) {
    m |= ((m << 1) & MX_L) | ((m >> 1) & MX_R);
    m |= ((m << 3) & MY_L) | ((m >> 3) & MY_R);
    m |= ((m << 9) & M27)  | (m >> 9);
    return m;
}
__device__ __forceinline__ unsigned dil18(unsigned m) {
    unsigned ax = m | ((m << 1) & MX_L) | ((m >> 1) & MX_R);          // Dx
    unsigned ay = m | ((m << 3) & MY_L) | ((m >> 3) & MY_R);          // Dy
    unsigned dxy = ax | ((ax << 3) & MY_L) | ((ax >> 3) & MY_R);      // DyDx
    unsigned dxz = ax | ((ax << 9) & M27)  | (ax >> 9);               // DzDx
    unsigned dyz = ay | ((ay << 9) & M27)  | (ay >> 9);               // DzDy
    return dxy | dxz | dyz;   // all offsets with >=1 zero component
}

__device__ __forceinline__ bool single18(unsigned m) {
    if (!m) return false;
    unsigned c = m & (~m + 1u);
    for (;;) {
        unsigned n = dil18(c) & m;
        if (n == m) return true;
        if (n == c) return false;
        c = n;
    }
}
__device__ __forceinline__ bool single26(unsigned m) {
    if (!m) return false;
    unsigned c = m & (~m + 1u);
    for (;;) {
        unsigned n = dil26(c) & m;
        if (n == m) return true;
        if (n == c) return false;
        c = n;
    }
}

// ---------------------------------------------------------------------------
// Phase 3: non-simple maps + weighted BCE + mean.
// Region 8x8x4 per block (1024 blocks = 4 blocks/CU, 1 voxel/thread/field),
// halo 10x10x6 = 600 ints per field. R4: flatten dispatch dropped -- halo
// load batches all independent loads, then does the (short) chases here.
// Halo layout: i = hz*100 + hy*10 + hx; window corner of (lx,ly,lz) = base,
// center = base + 111.
// ---------------------------------------------------------------------------
#define HV2 600   // 10*10*6

__global__ __launch_bounds__(256, 4)
void finalize_kernel(const float* __restrict__ pred,
                     const float* __restrict__ lab,
                     const int* __restrict__ LP,
                     const int* __restrict__ LL,
                     float* __restrict__ out) {
    __shared__ int sP[HV2], sL[HV2];
    __shared__ float s_part[4];
    int t = threadIdx.x;
    int b = blockIdx.x;                          // 8 x 8 x 16 regions
    int rx = b & 7, ry = (b >> 3) & 7, rz = b >> 6;
    int x0 = rx << 3, y0 = ry << 3, z0 = rz << 2;

    // batched halo load: all independent loads first, then the chases
    int pv[3], lv[3];
#pragma unroll
    for (int j = 0; j < 3; ++j) {
        int i = t + (j << 8);
        if (i < HV2) {
            int hx = i % 10, rr = i / 10, hy = rr % 10, hz = rr / 10;
            int gx = x0 + hx - 1; gx = gx < 0 ? 0 : (gx > 63 ? 63 : gx);
            int gy = y0 + hy - 1; gy = gy < 0 ? 0 : (gy > 63 ? 63 : gy);
            int gz = z0 + hz - 1; gz = gz < 0 ? 0 : (gz > 63 ? 63 : gz);
            int gv = (gz << 12) | (gy << 6) | gx;
            pv[j] = LP[gv];
            lv[j] = LL[gv];
        }
    }
#pragma unroll
    for (int j = 0; j < 3; ++j) {
        int i = t + (j << 8);
        if (i < HV2) {
            int p = pv[j];
            if (p >= 0) p = chase(LP, p);
            sP[i] = p;
            p = lv[j];
            if (p >= 0) p = chase(LL, p);
            sL[i] = p;
        }
    }
    __syncthreads();

    float acc;
    {
        int l = t;                               // region 8x8x4: 256 voxels
        int lx = l & 7, ly = (l >> 3) & 7, lz = l >> 6;
        int x = x0 | lx, y = y0 | ly, z = z0 | lz;
        int v = (z << 12) | (y << 6) | x;
        int base = lz * 100 + ly * 10 + lx;      // (-1,-1,-1) corner

        bool nsP = false, nsL = false;
        {
            int c = sP[base + 111];              // center
            if (c >= 0) {
                unsigned m1 = 0, m2 = 0; int k = 0;
#pragma unroll
                for (int kz = 0; kz < 3; ++kz)
#pragma unroll
                    for (int ky = 0; ky < 3; ++ky)
#pragma unroll
                        for (int kx = 0; kx < 3; ++kx, ++k) {
                            int w = sP[base + kz * 100 + ky * 10 + kx];
                            m1 |= (unsigned)(w != c) << k;
                            m2 |= (unsigned)(w == c) << k;
                        }
                m2 &= ~(1u << 13);               // drop center
                nsP = !(single18(m1) && single26(m2));
            }
        }
        {
            int c = sL[base + 111];
            if (c >= 0) {
                unsigned m1 = 0, m2 = 0; int k = 0;
#pragma unroll
                for (int kz = 0; kz < 3; ++kz)
#pragma unroll
                    for (int ky = 0; ky < 3; ++ky)
#pragma unroll
                        for (int kx = 0; kx < 3; ++kx, ++k) {
                            int w = sL[base + kz * 100 + ky * 10 + kx];
                            m1 |= (unsigned)(w != c) << k;
                            m2 |= (unsigned)(w == c) << k;
                        }
                m2 &= ~(1u << 13);
                nsL = !(single18(m1) && single26(m2));
            }
        }

        float p = pred[v], lvf = lab[v];
        float cost = fmaxf(p, 0.0f) - p * lvf + log1pf(__expf(-fabsf(p)));
        acc = ((nsP || nsL) ? 5.0f : 1.0f) * cost;
    }

#pragma unroll
    for (int off = 32; off > 0; off >>= 1)
        acc += __shfl_down(acc, off, 64);
    if ((t & 63) == 0) s_part[t >> 6] = acc;
    __syncthreads();
    if (t == 0) {
        float s = s_part[0] + s_part[1] + s_part[2] + s_part[3];
        atomicAdd(out, s * (1.0f / (float)NVOX));
    }
}

extern "C" void kernel_launch(void* const* d_in, const int* in_sizes, int n_in,
                              void* d_out, int out_size, void* d_ws, size_t ws_size,
                              hipStream_t stream) {
    const float* pred = (const float*)d_in[0];   // 'prediction'
    const float* lab  = (const float*)d_in[1];   // 'label'
    float* out = (float*)d_out;

    int* LP = (int*)d_ws;          // NVOX ints
    int* LL = LP + NVOX;           // NVOX ints  (2 MiB total)

    hipLaunchKernelGGL(local_ccl, dim3(128, 2), dim3(512), 0, stream,
                       pred, lab, LP, LL, out);
    hipLaunchKernelGGL(boundary_link, dim3(EPF / 256, 2), dim3(256), 0, stream,
                       LP, LL);
    hipLaunchKernelGGL(finalize_kernel, dim3(1024), dim3(256), 0, stream,
                       pred, lab, LP, LL, out);
}